// Round 3
// baseline (525.974 us; speedup 1.0000x reference)
//
#include <hip/hip_runtime.h>

// Problem constants
#define B_  4096
#define D_  1024
#define R_  2048
#define MAXD 2560

typedef _Float16 half8 __attribute__((ext_vector_type(8)));  // 8 fp16 = 4 VGPRs (MFMA frag)
typedef _Float16 half4 __attribute__((ext_vector_type(4)));  // 8-byte LDS store
typedef float    f32x4 __attribute__((ext_vector_type(4)));

constexpr int BM = 128;      // M tile (batch rows)
constexpr int BN = 64;       // N tile (reservoir cols)
constexpr int BK = 32;       // K chunk (elems)
constexpr int SAS = 40;      // padded LDS row stride (halves): 80 B, keeps b128 reads 16B-aligned

__device__ inline float sigmoidf_(float x) { return 1.0f / (1.0f + expf(-x)); }

// Fused: pre = X*Win^T + prev*Wres^T (K=3072), gates = X*Wgate^T (K=1024, 3 sets),
// state = o*( 0.9*f*prev + 0.1*tanh(i*pre) ), spike-subtract, fp32 store.
// fp32-faithful accuracy via 2-term fp16 split + 3 MFMAs (hh, lh, hl); lo*lo dropped
// (error ~1e-7, below the fp32 accumulation floor of ~2e-6).
__global__ __launch_bounds__(256, 2)
void reservoir_fused(const float* __restrict__ X,     // B x D
                     const float* __restrict__ P,     // B x MAXD (use first R cols)
                     const float* __restrict__ Win,   // R x D
                     const float* __restrict__ Wres,  // R x R
                     const float* __restrict__ Wg,    // 3R x D
                     float* __restrict__ out)         // B x MAXD
{
    __shared__ _Float16 sAh[BM * SAS];        // 10240 B
    __shared__ _Float16 sAl[BM * SAS];        // 10240 B
    __shared__ _Float16 sWh[4][BN * SAS];     // 20480 B  (set 0 = pre-weights, 1..3 = i/f/o)
    __shared__ _Float16 sWl[4][BN * SAS];     // 20480 B   -> total 61440 B, 2 blocks/CU

    const int tid  = threadIdx.x;
    const int lane = tid & 63;
    const int wv   = tid >> 6;                      // wave id 0..3
    const int m0   = blockIdx.y * BM;
    const int n0   = blockIdx.x * BN;

    f32x4 acc[4][2][4];                              // [set][mtile][ntile] -> 128 VGPRs
    #pragma unroll
    for (int s = 0; s < 4; ++s)
        #pragma unroll
        for (int mt = 0; mt < 2; ++mt)
            #pragma unroll
            for (int nt = 0; nt < 4; ++nt) acc[s][mt][nt] = (f32x4){0.f, 0.f, 0.f, 0.f};

    const int fr = lane & 15;            // fragment row within 16-tile
    const int fk = (lane >> 4) * 8;      // fragment k offset (quad*8)

    for (int k0 = 0; k0 < D_ + R_; k0 += BK) {
        const bool ph1 = (k0 < D_);

        // ---- stage A tile: 128 rows x 32 k; fp32 load -> fp16 hi/lo planes ----
        {
            const float* src; int ld, kc;
            if (ph1) { src = X; ld = D_;   kc = k0; }
            else     { src = P; ld = MAXD; kc = k0 - D_; }
            #pragma unroll
            for (int i = 0; i < 4; ++i) {
                int f = i * 256 + tid;
                int row = f >> 3, c4 = (f & 7) * 4;
                f32x4 v = *(const f32x4*)(src + (size_t)(m0 + row) * ld + kc + c4);
                half4 h, l;
                #pragma unroll
                for (int j = 0; j < 4; ++j) {
                    h[j] = (_Float16)v[j];
                    l[j] = (_Float16)(v[j] - (float)h[j]);
                }
                *(half4*)(&sAh[row * SAS + c4]) = h;
                *(half4*)(&sAl[row * SAS + c4]) = l;
            }
        }
        // ---- stage pre-weight tile (Win or Wres): 64 x 32 ----
        {
            const float* src; int ld, kc;
            if (ph1) { src = Win;  ld = D_; kc = k0; }
            else     { src = Wres; ld = R_; kc = k0 - D_; }
            #pragma unroll
            for (int i = 0; i < 2; ++i) {
                int f = i * 256 + tid;
                int row = f >> 3, c4 = (f & 7) * 4;
                f32x4 v = *(const f32x4*)(src + (size_t)(n0 + row) * ld + kc + c4);
                half4 h, l;
                #pragma unroll
                for (int j = 0; j < 4; ++j) {
                    h[j] = (_Float16)v[j];
                    l[j] = (_Float16)(v[j] - (float)h[j]);
                }
                *(half4*)(&sWh[0][row * SAS + c4]) = h;
                *(half4*)(&sWl[0][row * SAS + c4]) = l;
            }
        }
        // ---- stage gate weight tiles (phase 1 only): 3 x (64 x 32) ----
        if (ph1) {
            #pragma unroll
            for (int g = 0; g < 3; ++g)
                #pragma unroll
                for (int i = 0; i < 2; ++i) {
                    int f = i * 256 + tid;
                    int row = f >> 3, c4 = (f & 7) * 4;
                    f32x4 v = *(const f32x4*)(Wg + (size_t)(g * R_ + n0 + row) * D_ + k0 + c4);
                    half4 h, l;
                    #pragma unroll
                    for (int j = 0; j < 4; ++j) {
                        h[j] = (_Float16)v[j];
                        l[j] = (_Float16)(v[j] - (float)h[j]);
                    }
                    *(half4*)(&sWh[1 + g][row * SAS + c4]) = h;
                    *(half4*)(&sWl[1 + g][row * SAS + c4]) = l;
                }
        }
        __syncthreads();

        // ---- MFMA: one 16x16x32 k-step per chunk, 3-way split ----
        half8 ah0 = *(const half8*)(&sAh[(wv * 32 +      fr) * SAS + fk]);
        half8 al0 = *(const half8*)(&sAl[(wv * 32 +      fr) * SAS + fk]);
        half8 ah1 = *(const half8*)(&sAh[(wv * 32 + 16 + fr) * SAS + fk]);
        half8 al1 = *(const half8*)(&sAl[(wv * 32 + 16 + fr) * SAS + fk]);

        const int nsets = ph1 ? 4 : 1;
        #pragma unroll
        for (int s = 0; s < 4; ++s) {
            if (s < nsets) {
                #pragma unroll
                for (int nt = 0; nt < 4; ++nt) {
                    half8 bh = *(const half8*)(&sWh[s][(nt * 16 + fr) * SAS + fk]);
                    half8 bl = *(const half8*)(&sWl[s][(nt * 16 + fr) * SAS + fk]);
                    acc[s][0][nt] = __builtin_amdgcn_mfma_f32_16x16x32_f16(ah0, bh, acc[s][0][nt], 0, 0, 0);
                    acc[s][0][nt] = __builtin_amdgcn_mfma_f32_16x16x32_f16(al0, bh, acc[s][0][nt], 0, 0, 0);
                    acc[s][0][nt] = __builtin_amdgcn_mfma_f32_16x16x32_f16(ah0, bl, acc[s][0][nt], 0, 0, 0);
                    acc[s][1][nt] = __builtin_amdgcn_mfma_f32_16x16x32_f16(ah1, bh, acc[s][1][nt], 0, 0, 0);
                    acc[s][1][nt] = __builtin_amdgcn_mfma_f32_16x16x32_f16(al1, bh, acc[s][1][nt], 0, 0, 0);
                    acc[s][1][nt] = __builtin_amdgcn_mfma_f32_16x16x32_f16(ah1, bl, acc[s][1][nt], 0, 0, 0);
                }
            }
        }
        __syncthreads();
    }

    // ---- epilogue: C/D layout col=lane&15, row=quad*4+reg (m89-verified) ----
    const int qd = lane >> 4;
    #pragma unroll
    for (int mt = 0; mt < 2; ++mt)
        #pragma unroll
        for (int nt = 0; nt < 4; ++nt)
            #pragma unroll
            for (int r = 0; r < 4; ++r) {
                int row = m0 + wv * 32 + mt * 16 + qd * 4 + r;   // batch index
                int col = n0 + nt * 16 + fr;                      // reservoir index
                float pre = acc[0][mt][nt][r];
                float ig  = sigmoidf_(acc[1][mt][nt][r]);
                float fg  = sigmoidf_(acc[2][mt][nt][r]);
                float og  = sigmoidf_(acc[3][mt][nt][r]);
                float pv  = P[(size_t)row * MAXD + col];          // exact fp32 prev
                float st  = 0.9f * (fg * pv) + 0.1f * tanhf(ig * pre);
                st *= og;
                if (st > 0.5f) st -= 0.5f;
                out[(size_t)row * MAXD + col] = st;
            }
}

// Zero the pad region out[:, 2048:2560] (harness poisons d_out with 0xAA).
__global__ void pad_zero(float* __restrict__ out) {
    int idx = blockIdx.x * 256 + threadIdx.x;
    int row = idx >> 7;
    int c   = (idx & 127) * 4;
    *(f32x4*)(&out[(size_t)row * MAXD + R_ + c]) = (f32x4){0.f, 0.f, 0.f, 0.f};
}

extern "C" void kernel_launch(void* const* d_in, const int* in_sizes, int n_in,
                              void* d_out, int out_size, void* d_ws, size_t ws_size,
                              hipStream_t stream) {
    const float* X    = (const float*)d_in[0];
    const float* P    = (const float*)d_in[1];
    const float* Win  = (const float*)d_in[2];
    const float* Wres = (const float*)d_in[3];
    const float* Wg   = (const float*)d_in[4];
    float* out        = (float*)d_out;

    pad_zero<<<2048, 256, 0, stream>>>(out);
    dim3 grid(R_ / BN, B_ / BM);   // (32, 32) = 1024 blocks
    reservoir_fused<<<grid, 256, 0, stream>>>(X, P, Win, Wres, Wg, out);
}